// Round 10
// baseline (76.748 us; speedup 1.0000x reference)
//
#include <hip/hip_runtime.h>
#include <math.h>

#define N_QUBITS 11
#define DIM 2048

// ---------------------------------------------------------------------------
// TRANSFER-MATRIX, FULLY TABULATED (R8/R9 algebra, validated absmax 6e-5).
//
//   out[j] = Re( r(b0) · M1(b1)·...·M9(b9) · t10(b10) ),   b = j ^ (j<<1)
//   M_q(b) = [[d0,d1],[e0,e1]],  d0=V[b,0]c(0), d1=V[b,1]c(1),
//                                e0=V[b,0]c(1), e1=V[b,1]c(0)
//
//   H[b0..b4]    = r(b0)·M1·M2·M3·M4      (32 row-vectors, threads 0-31)
//   Tail[b5..b10]= M5·...·M9·t10          (64 col-vectors, threads 64-127)
//   out = Re( H · Tail )                  (4 FMA per output)
//
// R10 change (critical-path only; R9 main loop untouched): H and Tail are
// built CONCURRENTLY on different waves, Tail directly as a 5-step matvec
// chain (no Am/Bm/Cv pair tables), cutting one of three barriers. With all
// 4096 blocks co-resident (2.2 KB LDS, exactly 32 waves/CU), kernel time is
// serial-path latency + the 5.2 us HBM write floor, so fewer barriers and a
// shorter chain are what remain.
//
// j = 1024w + 16L + n:  b0..b3 = bits of (n^(n<<1))&15, b4 = L0^n3,
// b5..b9 = bits of z = (L^(L>>1))&31, b10 = w^L5.
// ---------------------------------------------------------------------------

__global__ __launch_bounds__(128)
void pqc_sim_kernel(const float* __restrict__ theta,
                    const int* __restrict__ positions,
                    float* __restrict__ out)
{
    __shared__ __align__(16) float K[N_QUBITS][2][8];  // transfer coeffs
    __shared__ __align__(16) float H[32][4];           // head row-vectors
    __shared__ __align__(16) float Tail[64][4];        // tail col-vectors

    const int t   = threadIdx.x;
    const int b   = blockIdx.x;
    const int pos = positions[b];

    // Hoisted main-loop constants (no LDS dependence)
    const int w = t >> 6, L = t & 63;
    const int z    = (L ^ (L >> 1)) & 31;
    const int tidx = z | (((w ^ (L >> 5)) & 1) << 5);
    const int L0h  = (L & 1) << 4;
    float* orow = out + (size_t)b * DIM + w * 1024 + L * 16;

    // ---- Phase 1: K rows straight from theta (44 threads; validated R9) ----
    if (t < 44) {
        const int q = t >> 1, bsel = t & 1;
        const float* th1 = theta + ((size_t)pos * 2 + 0) * (3 * N_QUBITS) + 3 * q;
        const float* th2 = theta + ((size_t)pos * 2 + 1) * (3 * N_QUBITS) + 3 * q;

        float c0r, c0i, c1r, c1i;
        {
            float sa, ca, sb, cb, sg, cg;
            sincosf(th1[0] * 0.5f, &sa, &ca);
            sincosf(th1[1] * 0.5f, &sb, &cb);
            sincosf(th1[2] * 0.5f, &sg, &cg);
            const float m00r =  cb * ca, m00i =  sb * sa;
            const float m10r =  sb * ca, m10i = -cb * sa;
            c0r = m00r * cg + m00i * sg;  c0i = m00i * cg - m00r * sg;
            c1r = m10r * cg - m10i * sg;  c1i = m10i * cg + m10r * sg;
        }
        float v0r, v0i, v1r, v1i;
        {
            float sa, ca, sb, cb, sg, cg;
            sincosf(th2[0] * 0.5f, &sa, &ca);
            sincosf(th2[1] * 0.5f, &sb, &cb);
            sincosf(th2[2] * 0.5f, &sg, &cg);
            const float m00r =  cb * ca, m00i =  sb * sa;
            const float m01r = -sb * ca, m01i = -cb * sa;
            const float m10r =  sb * ca, m10i = -cb * sa;
            const float m11r =  cb * ca, m11i = -sb * sa;
            if (bsel == 0) {
                v0r = m00r * cg + m00i * sg;  v0i = m00i * cg - m00r * sg;
                v1r = m01r * cg + m01i * sg;  v1i = m01i * cg - m01r * sg;
            } else {
                v0r = m10r * cg - m10i * sg;  v0i = m10i * cg + m10r * sg;
                v1r = m11r * cg - m11i * sg;  v1i = m11i * cg + m11r * sg;
            }
        }
        K[q][bsel][0] = v0r * c0r - v0i * c0i;
        K[q][bsel][1] = v0r * c0i + v0i * c0r;
        K[q][bsel][2] = v1r * c1r - v1i * c1i;
        K[q][bsel][3] = v1r * c1i + v1i * c1r;
        K[q][bsel][4] = v0r * c1r - v0i * c1i;
        K[q][bsel][5] = v0r * c1i + v0i * c1r;
        K[q][bsel][6] = v1r * c0r - v1i * c0i;
        K[q][bsel][7] = v1r * c0i + v1i * c0r;
    }
    __syncthreads();

    // ---- Phase 2 (single barrier phase, waves in parallel):
    //      wave 0 / t<32 : H rows;   wave 1 / t>=64 : Tail chains ----
    if (t < 32) {
        float ar = K[0][t & 1][0], ai = K[0][t & 1][1];
        float br = K[0][t & 1][2], bi = K[0][t & 1][3];
        #pragma unroll
        for (int q = 1; q < 5; ++q) {
            const float* Kq = &K[q][(t >> q) & 1][0];
            const float d0r = Kq[0], d0i = Kq[1], d1r = Kq[2], d1i = Kq[3];
            const float e0r = Kq[4], e0i = Kq[5], e1r = Kq[6], e1i = Kq[7];
            const float nar = ar * d0r - ai * d0i + br * e0r - bi * e0i;
            const float nai = ar * d0i + ai * d0r + br * e0i + bi * e0r;
            const float nbr = ar * d1r - ai * d1i + br * e1r - bi * e1i;
            const float nbi = ar * d1i + ai * d1r + br * e1i + bi * e1r;
            ar = nar; ai = nai; br = nbr; bi = nbi;
        }
        H[t][0] = ar; H[t][1] = ai; H[t][2] = br; H[t][3] = bi;
    } else if (t >= 64) {
        // Tail[e] = M5(e0)·M6(e1)·M7(e2)·M8(e3)·M9(e4)·t10(e5)
        const int e = t - 64;
        const float* Kt = &K[10][(e >> 5) & 1][0];
        float T0r = Kt[0] + Kt[2], T0i = Kt[1] + Kt[3];   // t10 = (d0+d1, e0+e1)
        float T1r = Kt[4] + Kt[6], T1i = Kt[5] + Kt[7];
        #pragma unroll
        for (int k = 4; k >= 0; --k) {                    // q = 9 down to 5
            const float* Kq = &K[5 + k][(e >> k) & 1][0];
            const float nr0 = Kq[0] * T0r - Kq[1] * T0i + Kq[2] * T1r - Kq[3] * T1i;
            const float ni0 = Kq[0] * T0i + Kq[1] * T0r + Kq[2] * T1i + Kq[3] * T1r;
            const float nr1 = Kq[4] * T0r - Kq[5] * T0i + Kq[6] * T1r - Kq[7] * T1i;
            const float ni1 = Kq[4] * T0i + Kq[5] * T0r + Kq[6] * T1i + Kq[7] * T1r;
            T0r = nr0; T0i = ni0; T1r = nr1; T1i = ni1;
        }
        Tail[e][0] = T0r; Tail[e][1] = T0i; Tail[e][2] = T1r; Tail[e][3] = T1i;
    }
    __syncthreads();

    // ---- Main: 1 Tail read + 16 H reads + 64 FMA + 4 stores (R9-validated) ----
    const float4 T = *(const float4*)&Tail[tidx][0];
    #pragma unroll
    for (int g = 0; g < 4; ++g) {
        float4 o;
        #pragma unroll
        for (int e = 0; e < 4; ++e) {
            const int n = 4 * g + e;
            const int hidx = (((n ^ (n << 1)) & 15) | ((n >> 3) << 4)) ^ L0h;
            const float4 h = *(const float4*)&H[hidx][0];
            const float v = h.x * T.x - h.y * T.y + h.z * T.z - h.w * T.w;
            if (e == 0) o.x = v; else if (e == 1) o.y = v;
            else if (e == 2) o.z = v; else o.w = v;
        }
        *(float4*)(orow + 4 * g) = o;
    }
}

extern "C" void kernel_launch(void* const* d_in, const int* in_sizes, int n_in,
                              void* d_out, int out_size, void* d_ws, size_t ws_size,
                              hipStream_t stream)
{
    const float* theta     = (const float*)d_in[0];
    const int*   positions = (const int*)d_in[1];
    float*       out       = (float*)d_out;
    const int B = in_sizes[1];   // 4096

    pqc_sim_kernel<<<B, 128, 0, stream>>>(theta, positions, out);
}